// Round 8
// baseline (445.685 us; speedup 1.0000x reference)
//
#include <hip/hip_runtime.h>

#define LL 384
#define NH 8

typedef const float* fp32p;

// ---------------- K0: zero the cat buffer (atomic accumulation target) ----------
__global__ __launch_bounds__(256) void k_zero(float4* p)
{
  p[(size_t)blockIdx.x*256 + threadIdx.x] = make_float4(0.f, 0.f, 0.f, 0.f);
}

// ---------------- K1: projections + point rotation ----------------
// grid 768 (b*L+l), block 128
__global__ __launch_bounds__(128) void k_proj(
    fp32p x, fp32p r, fp32p tvec,
    fp32p Wqs, fp32p Wks, fp32p Wvs,
    fp32p Wqp, fp32p Wkp, fp32p Wvp,
    float* qs, float* ks, float* vs,
    float* qp, float* kp, float* vp)
{
  int bl = blockIdx.x;
  int t = threadIdx.x;
  __shared__ float xs[128];
  __shared__ float yq[96], yk[96], yv[96];
  xs[t] = x[bl*128 + t];
  __syncthreads();
  float aq = 0.f, ak = 0.f, av = 0.f;
  for (int d = 0; d < 128; ++d) {
    float xv = xs[d];
    aq += xv * Wqs[d*128 + t];
    ak += xv * Wks[d*128 + t];
    av += xv * Wvs[d*128 + t];
  }
  int b = bl / LL, l = bl - (bl / LL) * LL;
  int n = t >> 4, dhs = t & 15;
  int rowbase = (b*NH + n)*LL + l;
  qs[rowbase*16 + dhs] = aq;
  ks[rowbase*16 + dhs] = ak;
  vs[rowbase*16 + dhs] = av;
  if (t < 96) {
    float pq = 0.f, pk = 0.f, pv = 0.f;
    for (int d = 0; d < 128; ++d) {
      float xv = xs[d];
      pq += xv * Wqp[d*96 + t];
      pk += xv * Wkp[d*96 + t];
      pv += xv * Wvp[d*96 + t];
    }
    yq[t] = pq; yk[t] = pk; yv[t] = pv;
  }
  __syncthreads();
  if (t < 96) {
    int np = t / 12;
    int rem = t - np*12;
    int p = rem / 3, c = rem - p*3;
    float rr0 = r[(bl*3 + 0)*3 + c];
    float rr1 = r[(bl*3 + 1)*3 + c];
    float rr2 = r[(bl*3 + 2)*3 + c];
    float tt  = tvec[bl*3 + c];
    int base = np*12 + p*3;
    int prow = (b*NH + np)*LL + l;
    qp[prow*12 + p*3 + c] = yq[base]*rr0 + yq[base+1]*rr1 + yq[base+2]*rr2 + tt;
    kp[prow*12 + p*3 + c] = yk[base]*rr0 + yk[base+1]*rr1 + yk[base+2]*rr2 + tt;
    vp[prow*12 + p*3 + c] = yv[base]*rr0 + yv[base+1]*rr1 + yv[base+2]*rr2 + tt;
  }
}

// ---------------- K2: all logits (bias + scalar dot + point dist) ----------------
// grid 576, block 256; thread handles (b,i,j0) and (b,i,j0+192)
__global__ __launch_bounds__(256) void k_logit(
    fp32p e, fp32p Wb, fp32p gamma,
    const float* qs, const float* ks, const float* qp, const float* kp,
    float* attn)
{
  __shared__ float WbS[1024];
  int t = threadIdx.x;
  #pragma unroll
  for (int u = 0; u < 4; ++u) WbS[t + u*256] = Wb[t + u*256];
  __syncthreads();
  int gtid = blockIdx.x*256 + t;                 // 147456 = 768 * 192
  int bi = gtid / 192, j0 = gtid - (gtid / 192)*192;
  int b = bi / LL, i = bi - (bi / LL)*LL;
  const float4* er0 = reinterpret_cast<const float4*>(e + ((size_t)bi*LL + j0)*128);
  const float4* er1 = reinterpret_cast<const float4*>(e + ((size_t)bi*LL + j0 + 192)*128);
  float acc0[8] = {0,0,0,0,0,0,0,0};
  float acc1[8] = {0,0,0,0,0,0,0,0};
  for (int d4 = 0; d4 < 32; ++d4) {
    float4 e0 = er0[d4], e1 = er1[d4];
    float a0[4] = {e0.x, e0.y, e0.z, e0.w};
    float a1[4] = {e1.x, e1.y, e1.z, e1.w};
    #pragma unroll
    for (int k = 0; k < 4; ++k) {
      int d = d4*4 + k;
      float4 w0 = *reinterpret_cast<const float4*>(&WbS[d*8]);
      float4 w1 = *reinterpret_cast<const float4*>(&WbS[d*8 + 4]);
      acc0[0] += a0[k]*w0.x; acc0[1] += a0[k]*w0.y; acc0[2] += a0[k]*w0.z; acc0[3] += a0[k]*w0.w;
      acc0[4] += a0[k]*w1.x; acc0[5] += a0[k]*w1.y; acc0[6] += a0[k]*w1.z; acc0[7] += a0[k]*w1.w;
      acc1[0] += a1[k]*w0.x; acc1[1] += a1[k]*w0.y; acc1[2] += a1[k]*w0.z; acc1[3] += a1[k]*w0.w;
      acc1[4] += a1[k]*w1.x; acc1[5] += a1[k]*w1.y; acc1[6] += a1[k]*w1.z; acc1[7] += a1[k]*w1.w;
    }
  }
  #pragma unroll
  for (int n = 0; n < 8; ++n) {
    size_t rq = (size_t)(b*NH + n)*LL + i;
    const float4* q4 = reinterpret_cast<const float4*>(qs + rq*16);
    float4 q0 = q4[0], q1 = q4[1], q2 = q4[2], q3 = q4[3];
    const float4* p4 = reinterpret_cast<const float4*>(qp + rq*12);
    float4 p0 = p4[0], p1 = p4[1], p2 = p4[2];
    float qq = p0.x*p0.x + p0.y*p0.y + p0.z*p0.z + p0.w*p0.w
             + p1.x*p1.x + p1.y*p1.y + p1.z*p1.z + p1.w*p1.w
             + p2.x*p2.x + p2.y*p2.y + p2.z*p2.z + p2.w*p2.w;
    float coef = -0.125f * gamma[n];
    #pragma unroll
    for (int jj = 0; jj < 2; ++jj) {
      int j = j0 + jj*192;
      size_t rk = (size_t)(b*NH + n)*LL + j;
      const float4* k4  = reinterpret_cast<const float4*>(ks + rk*16);
      const float4* kp4 = reinterpret_cast<const float4*>(kp + rk*12);
      float4 k0 = k4[0], k1 = k4[1], k2 = k4[2], k3 = k4[3];
      float dots = q0.x*k0.x + q0.y*k0.y + q0.z*k0.z + q0.w*k0.w
                 + q1.x*k1.x + q1.y*k1.y + q1.z*k1.z + q1.w*k1.w
                 + q2.x*k2.x + q2.y*k2.y + q2.z*k2.z + q2.w*k2.w
                 + q3.x*k3.x + q3.y*k3.y + q3.z*k3.z + q3.w*k3.w;
      float4 c0 = kp4[0], c1 = kp4[1], c2 = kp4[2];
      float cross = p0.x*c0.x + p0.y*c0.y + p0.z*c0.z + p0.w*c0.w
                  + p1.x*c1.x + p1.y*c1.y + p1.z*c1.z + p1.w*c1.w
                  + p2.x*c2.x + p2.y*c2.y + p2.z*c2.z + p2.w*c2.w;
      float kk = c0.x*c0.x + c0.y*c0.y + c0.z*c0.z + c0.w*c0.w
               + c1.x*c1.x + c1.y*c1.y + c1.z*c1.z + c1.w*c1.w
               + c2.x*c2.x + c2.y*c2.y + c2.z*c2.z + c2.w*c2.w;
      float bias = jj ? acc1[n] : acc0[n];
      attn[((size_t)(b*NH + n)*LL + i)*LL + j] =
          0.57735027f * (0.25f*dots + bias + coef*(qq + kk - 2.f*cross));
    }
  }
}

// ---------------- K3: softmax in place; one wave per (b,n,i) row; grid 1536 ----
__global__ __launch_bounds__(256) void k_soft(float* attn)
{
  int row = blockIdx.x*4 + (threadIdx.x >> 6);
  int lane = threadIdx.x & 63;
  float* arow = attn + (size_t)row*LL;
  float v[6];
  #pragma unroll
  for (int q = 0; q < 6; ++q) v[q] = arow[lane + q*64];
  float m = v[0];
  #pragma unroll
  for (int q = 1; q < 6; ++q) m = fmaxf(m, v[q]);
  #pragma unroll
  for (int off = 32; off >= 1; off >>= 1) m = fmaxf(m, __shfl_xor(m, off, 64));
  float s = 0.f;
  #pragma unroll
  for (int q = 0; q < 6; ++q) { v[q] = __expf(v[q] - m); s += v[q]; }
  #pragma unroll
  for (int off = 32; off >= 1; off >>= 1) s += __shfl_xor(s, off, 64);
  float inv = 1.f / s;
  #pragma unroll
  for (int q = 0; q < 6; ++q) arow[lane + q*64] = v[q]*inv;
}

// ---------------- K4a: out_scalar = attn@vs, op = attn@vp ----------------
// thread per (row, dim32); grid 768, block 256
__global__ __launch_bounds__(256) void k_av(
    const float* attn, const float* vs, const float* vp, float* cat, float* opb)
{
  int tid = blockIdx.x*256 + threadIdx.x;
  int row = tid >> 5;
  int dim = tid & 31;
  if (dim >= 28) return;
  int i = row % LL;
  int bn = row / LL;
  int rowbase = bn * LL;
  const float* arow = attn + (size_t)row*LL;
  const float* src; int stride;
  if (dim < 16) { src = vs + (size_t)rowbase*16 + dim; stride = 16; }
  else          { src = vp + (size_t)rowbase*12 + (dim - 16); stride = 12; }
  float acc = 0.f;
  for (int j = 0; j < LL; ++j) acc += arow[j] * src[(size_t)j*stride];
  int b = bn >> 3, n = bn & 7;
  if (dim < 16) cat[((size_t)(b*LL + i))*1280 + n*16 + dim] = acc;
  else          opb[(size_t)row*12 + (dim - 16)] = acc;
}

// ---------------- K4b: out_pair = attn . e, j-sliced 4x, atomic accumulate ----
// grid 3072 = bi*4 + slice; block 256 = (n<<5) | d4
__global__ __launch_bounds__(256) void k_pair(fp32p e, const float* attn, float* cat)
{
  int blk = blockIdx.x;
  int bi = blk >> 2, s = blk & 3;
  int b = bi / LL, i = bi - (bi / LL)*LL;
  int t = threadIdx.x;
  __shared__ float attnS[768];         // 8 heads x 96 j
  #pragma unroll
  for (int u = 0; u < 3; ++u) {
    int idx = t + u*256;
    int n2 = idx / 96, jj = idx - n2*96;
    attnS[idx] = attn[((size_t)(b*NH + n2)*LL + i)*LL + s*96 + jj];
  }
  __syncthreads();
  int n = t >> 5, d4 = t & 31;
  const float4* e4 = reinterpret_cast<const float4*>(e) + ((size_t)bi*LL + s*96)*32 + d4;
  const float* an = attnS + n*96;
  float4 acc = make_float4(0.f, 0.f, 0.f, 0.f);
  for (int jj = 0; jj < 96; ++jj) {
    float4 ev = e4[(size_t)jj*32];
    float a = an[jj];
    acc.x += a*ev.x; acc.y += a*ev.y; acc.z += a*ev.z; acc.w += a*ev.w;
  }
  float* dst = cat + (size_t)bi*1280 + 128 + n*128 + d4*4;
  atomicAdd(dst + 0, acc.x);
  atomicAdd(dst + 1, acc.y);
  atomicAdd(dst + 2, acc.z);
  atomicAdd(dst + 3, acc.w);
}

// ---------------- K5: inverse point transform + norms ----------------
// op_local[c] = sum_k (op - t)[k] * r[b,i,c,k]   (einsum 'bnipk,bick->bnipc')
__global__ __launch_bounds__(256) void k_pt(const float* opb, fp32p r, fp32p tvec, float* cat)
{
  int tid = blockIdx.x*256 + threadIdx.x;    // 24576
  int p = tid & 3;
  int row = tid >> 2;
  int i = row % LL;
  int bn = row / LL;
  int b = bn >> 3, n = bn & 7;
  int bi = b*LL + i;
  float o[3];
  #pragma unroll
  for (int k = 0; k < 3; ++k)
    o[k] = opb[(size_t)row*12 + p*3 + k] - tvec[bi*3 + k];
  float loc[3];
  #pragma unroll
  for (int c = 0; c < 3; ++c) {
    float s = 0.f;
    #pragma unroll
    for (int k = 0; k < 3; ++k) s += o[k] * r[(bi*3 + c)*3 + k];   // r[b,i,c,k]
    loc[c] = s;
  }
  float* dst = cat + (size_t)bi*1280;
  dst[1152 + n*12 + p*3 + 0] = loc[0];
  dst[1152 + n*12 + p*3 + 1] = loc[1];
  dst[1152 + n*12 + p*3 + 2] = loc[2];
  dst[1248 + n*4 + p] = sqrtf(loc[0]*loc[0] + loc[1]*loc[1] + loc[2]*loc[2]);
}

// ---------------- K6: out = cat @ Wo + bo ----------------
// 8 rows/block, grid 96, block 256; 16-deep independent dwordx4 pipeline
__global__ __launch_bounds__(256) void k_out(const float* cat, fp32p Wo, fp32p bo,
                                             float* out)
{
  int r0 = blockIdx.x * 8;
  int t = threadIdx.x;
  __shared__ float catS[8*1280];       // 40 KB
  {
    const float4* c4 = reinterpret_cast<const float4*>(cat + (size_t)r0*1280);
    float4* s4 = reinterpret_cast<float4*>(catS);
    for (int idx = t; idx < 2560; idx += 256) s4[idx] = c4[idx];
  }
  __syncthreads();
  int row = t >> 5;                    // 0..7
  int cg  = t & 31;                    // col group (4 cols)
  const float* crow = catS + row*1280;
  const float4* w4 = reinterpret_cast<const float4*>(Wo) + cg;
  float ax = 0.f, ay = 0.f, az = 0.f, aw = 0.f;
  for (int k = 0; k < 1280; k += 16) {
    float4 w[16]; float a[16];
    #pragma unroll
    for (int u = 0; u < 16; ++u) { w[u] = w4[(k + u)*32]; a[u] = crow[k + u]; }
    #pragma unroll
    for (int u = 0; u < 16; ++u) {
      ax += a[u]*w[u].x; ay += a[u]*w[u].y; az += a[u]*w[u].z; aw += a[u]*w[u].w;
    }
  }
  float4 bv = reinterpret_cast<const float4*>(bo)[cg];
  float4 res = { ax + bv.x, ay + bv.y, az + bv.z, aw + bv.w };
  reinterpret_cast<float4*>(out + (size_t)(r0 + row)*128)[cg] = res;
}

extern "C" void kernel_launch(void* const* d_in, const int* in_sizes, int n_in,
                              void* d_out, int out_size, void* d_ws, size_t ws_size,
                              hipStream_t stream)
{
  fp32p x    = (fp32p)d_in[0];
  fp32p e    = (fp32p)d_in[1];
  fp32p r    = (fp32p)d_in[2];
  fp32p tv   = (fp32p)d_in[3];
  fp32p Wqs  = (fp32p)d_in[4];
  fp32p Wks  = (fp32p)d_in[5];
  fp32p Wvs  = (fp32p)d_in[6];
  fp32p Wb   = (fp32p)d_in[7];
  fp32p Wqp  = (fp32p)d_in[8];
  fp32p Wkp  = (fp32p)d_in[9];
  fp32p Wvp  = (fp32p)d_in[10];
  fp32p gam  = (fp32p)d_in[11];
  fp32p Wo   = (fp32p)d_in[12];
  fp32p bo   = (fp32p)d_in[13];
  float* out = (float*)d_out;

  // ws partition (floats); total ~15.7 MB
  float* qs   = (float*)d_ws;
  float* ks   = qs + 98304;            // 6144*16
  float* vs   = ks + 98304;
  float* qp   = vs + 98304;            // 6144*12
  float* kp   = qp + 73728;
  float* vp   = kp + 73728;
  float* attn = vp + 73728;            // 2*8*384*384
  float* opb  = attn + 2359296;        // 6144*12
  float* cat  = opb + 73728;           // 768*1280

  k_zero<<<960, 256, 0, stream>>>(reinterpret_cast<float4*>(cat));
  k_proj<<<768, 128, 0, stream>>>(x, r, tv, Wqs, Wks, Wvs, Wqp, Wkp, Wvp,
                                  qs, ks, vs, qp, kp, vp);
  k_logit<<<576, 256, 0, stream>>>(e, Wb, gam, qs, ks, qp, kp, attn);
  k_soft<<<1536, 256, 0, stream>>>(attn);
  k_av<<<768, 256, 0, stream>>>(attn, vs, vp, cat, opb);
  k_pair<<<3072, 256, 0, stream>>>(e, attn, cat);
  k_pt<<<96, 256, 0, stream>>>(opb, r, tv, cat);
  k_out<<<96, 256, 0, stream>>>(cat, Wo, bo, out);
}